// Round 13
// baseline (20.756 us; speedup 1.0000x reference)
//
#include <hip/hip_runtime.h>
#include <math.h>

#define NQ   10
#define NL   4
#define NREG 16   // 1024 amplitudes / 64 lanes
#define NPK  8    // 8 f32x2 pairs (SoA packing of adjacent j)
#define SPB  4    // samples (waves) per block

typedef float f32x2 __attribute__((ext_vector_type(2)));
typedef unsigned u32x2 __attribute__((ext_vector_type(2)));

// ---------------------------------------------------------------------------
// Compile-time GF(2) tracking of the CNOT rings.
// stored[q] = amp[L q]; gate on logical bit p pairs {q, q^m}, m = col p of
// L^-1; logical bit value = parity(row_p(L) & q). Layer 0 folded into init.
// Layer-3 gates commuting with <Z> (parity(sgn&m)==0) are deleted.
// ---------------------------------------------------------------------------
struct MaskTab { int m[NL * NQ]; int d[NL * NQ]; bool keep[NL * NQ]; int sgn; bool ok; };

constexpr MaskTab make_masks() {
    MaskTab t{};
    int L[NQ] = {}, Li[NQ] = {};
    for (int p = 0; p < NQ; ++p) { L[p] = 1 << p; Li[p] = 1 << p; }
    for (int l = 0; l < NL; ++l) {
        for (int w = 0; w < NQ; ++w) {
            int p = NQ - 1 - w;
            int mm = 0;
            for (int tt = 0; tt < NQ; ++tt) mm |= ((Li[tt] >> p) & 1) << tt;
            t.m[l * NQ + w] = mm;
            t.d[l * NQ + w] = L[p];
        }
        int r = (l % (NQ - 1)) + 1;
        for (int w = 0; w < NQ; ++w) {           // L <- P_l^-1 L
            int pc = NQ - 1 - w;
            int tq = w + r; if (tq >= NQ) tq -= NQ;
            int pt = NQ - 1 - tq;
            L[pt] ^= L[pc];
        }
        for (int w = 0; w < NQ; ++w) {           // Li <- Li P_l
            int pc = NQ - 1 - w;
            int tq = w + r; if (tq >= NQ) tq -= NQ;
            int pt = NQ - 1 - tq;
            for (int p = 0; p < NQ; ++p)
                Li[p] ^= ((Li[p] >> pt) & 1) << pc;
        }
    }
    t.sgn = L[0];
    for (int gi = 0; gi < NL * NQ; ++gi) {
        if (gi < NQ) { t.keep[gi] = false; continue; }            // layer 0 folded
        if (gi < (NL - 1) * NQ) { t.keep[gi] = true; continue; }
        t.keep[gi] = (__builtin_popcount((unsigned)(t.sgn & t.m[gi])) & 1) != 0;
    }
    bool ok = true;
    for (int p = 0; p < NQ; ++p) {
        int row = 0;
        for (int k = 0; k < NQ; ++k)
            if ((L[p] >> k) & 1) row ^= Li[k];
        if (row != (1 << p)) ok = false;
    }
    t.ok = ok;
    return t;
}

static constexpr MaskTab MK = make_masks();
static_assert(MK.ok, "GF(2) inverse check failed");

// ---------------------------------------------------------------------------
// Cross-lane xor-exchange, routed by compile-time mask:
//   bits 0-3 only   -> 1-2 v_mov_dpp            (VALU pipe)
//   bit 4, no bit 5 -> permlane16_swap + cndmask (+DPP for low bits)  (VALU)
//   bit 5 set       -> 1 ds_bpermute            (DS pipe, hoisted addr)
// DS load rebalance: only the bpermute gates remain on the contended DS pipe.
// ---------------------------------------------------------------------------
constexpr int dpp_direct(int m) {
    return m == 1 ? 0xB1 : m == 2 ? 0x4E : m == 3 ? 0x1B :
           m == 7 ? 0x141 : m == 8 ? 0x128 : m == 15 ? 0x140 : 0;
}
constexpr int dpp1(int m) {
    return dpp_direct(m)      ? dpp_direct(m) :
           dpp_direct(m ^ 8)  ? 0x128 :
           dpp_direct(m ^ 15) ? 0x140 : 0x141;
}
constexpr int dpp2(int m) {
    return dpp_direct(m)      ? 0 :
           dpp_direct(m ^ 8)  ? dpp_direct(m ^ 8) :
           dpp_direct(m ^ 15) ? dpp_direct(m ^ 15) : dpp_direct(m ^ 7);
}

template <int M>
__device__ __forceinline__ float xdpp(float v) {
    static_assert((M & ~15) == 0 && M != 0, "dpp mask must be 4-bit");
    int u = __builtin_amdgcn_mov_dpp(__float_as_int(v), dpp1(M), 0xF, 0xF, true);
    if constexpr (dpp2(M) != 0)
        u = __builtin_amdgcn_mov_dpp(u, dpp2(M), 0xF, 0xF, true);
    return __int_as_float(u);
}
template <int M>
__device__ __forceinline__ float xswz(float v) {
    static_assert((M & ~31) == 0 && M != 0, "swizzle mask must be 5-bit");
    return __int_as_float(__builtin_amdgcn_ds_swizzle(__float_as_int(v), (M << 10) | 0x1F));
}
// xor-16 (optionally + low bits) entirely on VALU: DPP for low bits, then
// permlane16_swap + cndmask for bit 4. Semantics verified in round 6.
template <int M>
__device__ __forceinline__ float xpl16(float v, int lane) {
    static_assert((M & 16) != 0 && (M & 32) == 0, "xpl16 mask needs bit4, no bit5");
    float w = v;
    if constexpr ((M & 15) != 0) w = xdpp<M & 15>(w);
#if __has_builtin(__builtin_amdgcn_permlane16_swap)
    unsigned u = __float_as_uint(w);
    u32x2 r = __builtin_amdgcn_permlane16_swap(u, u, false, false);
    u = (lane & 16) ? r[0] : r[1];
    return __uint_as_float(u);
#else
    (void)lane;
    return xswz<16>(w);
#endif
}
__device__ __forceinline__ float xbp(int bpa, float v) {
    return __int_as_float(__builtin_amdgcn_ds_bpermute(bpa, __float_as_int(v)));
}

__device__ __forceinline__ float fxor(float a, unsigned s) {
    return __uint_as_float(__float_as_uint(a) ^ s);
}
__device__ __forceinline__ f32x2 bc2(float v) { f32x2 r; r.x = v; r.y = v; return r; }
__device__ __forceinline__ f32x2 swap2(f32x2 v) { f32x2 r; r.x = v.y; r.y = v.x; return r; }
__device__ __forceinline__ f32x2 cmul(f32x2 a, f32x2 b) {
    f32x2 r;
    r.x = a.x * b.x - a.y * b.y;
    r.y = a.x * b.y + a.y * b.x;
    return r;
}
__device__ __forceinline__ float rdl(float v, int l) {
    return __uint_as_float((unsigned)__builtin_amdgcn_readlane((int)__float_as_uint(v), l));
}

// ---------------------------------------------------------------------------
// Polynomial sincos (no library calls, no branches).
// sincos_tiny: |a| < ~0.5 (gate angles < 0.06): err < 2e-9.
// sincos_q:    a in [0, pi/2] (RX encoding): half-angle + deg-7/8, err ~3e-7.
// ---------------------------------------------------------------------------
__device__ __forceinline__ void sincos_tiny(float a, float* s, float* c) {
    float t = a * a;
    *s = a * fmaf(t, fmaf(t, 8.3333333e-3f, -0.16666667f), 1.0f);
    *c = fmaf(t, fmaf(t, fmaf(t, -1.3888889e-3f, 4.1666668e-2f), -0.5f), 1.0f);
}
__device__ __forceinline__ void sincos_q(float a, float* s, float* c) {
    float h = 0.5f * a, u = h * h;
    float sh = h * fmaf(u, fmaf(u, fmaf(u, -1.9841270e-4f, 8.3333333e-3f), -0.16666667f), 1.0f);
    float ch = fmaf(u, fmaf(u, fmaf(u, fmaf(u, 2.4801587e-5f, -1.3888889e-3f),
                                    4.1666668e-2f), -0.5f), 1.0f);
    *s = 2.0f * sh * ch;
    *c = fmaf(-2.0f * sh, sh, 1.0f);
}

// ---------------------------------------------------------------------------
// One gate on SoA state: X[k]/Y[k] hold re/im of amplitudes j=2k, 2k+1.
// Compute phase is pure element-wise vector FMA (v_pk_fma_f32):
//   nX = g00x*sX - scyv*sY + pcxv*pX - g01y*pY
//   nY = g00x*sY + scyv*sX + pcxv*pY + g01y*pX
// ---------------------------------------------------------------------------
template <int GI>
__device__ __forceinline__ void apply_gate(f32x2 (&X)[NPK], f32x2 (&Y)[NPK],
                                           float g00x_r, float g00y_r,
                                           float g01x_r, float g01y_r, int lane) {
    if constexpr (MK.keep[GI]) {
        constexpr int m     = MK.m[GI];
        constexpr int d     = MK.d[GI];
        constexpr int mreg  = (m >> 6) & 15;
        constexpr int mlane = m & 63;
        constexpr int dreg  = (d >> 6) & 15;
        constexpr int dlane = d & 63;
        constexpr int  kreg  = mreg >> 1;          // pair-index xor
        constexpr bool kswap = (mreg & 1) != 0;    // within-pair half swap
        constexpr bool useDPP  = (mlane != 0) && ((mlane & 48) == 0);
        constexpr bool usePL16 = (mlane != 0) && !useDPP && ((mlane & 32) == 0);
        constexpr bool useBP   = (mlane != 0) && !useDPP && !usePL16;

        const float g00x = rdl(g00x_r, GI);        // uniform broadcast, no DS
        const float g00y = rdl(g00y_r, GI);
        const float g01x = rdl(g01x_r, GI);
        const float g01y = rdl(g01y_r, GI);

        const int bl = __popc(dlane & lane) & 1;   // lane part of bit value
        const unsigned s0 = (unsigned)bl << 31;
        const float scy0 = fxor(g00y, s0), pcx0 = fxor(g01x, s0);
        const float scy1 = fxor(scy0, 0x80000000u), pcx1 = fxor(pcx0, 0x80000000u);

        // per-pair sign-vector variants (A: v(2k)=0, B: v(2k)=1)
        f32x2 scyA, scyB, pcxA, pcxB;
        if constexpr (dreg & 1) {                   // alternating within pair
            scyA.x = scy0; scyA.y = scy1;  scyB.x = scy1; scyB.y = scy0;
            pcxA.x = pcx0; pcxA.y = pcx1;  pcxB.x = pcx1; pcxB.y = pcx0;
        } else {                                    // uniform within pair
            scyA = bc2(scy0); scyB = bc2(scy1);
            pcxA = bc2(pcx0); pcxB = bc2(pcx1);
        }
        const f32x2 g00xv = bc2(g00x);
        const f32x2 g01yv = bc2(g01y);

        [[maybe_unused]] int bpa = 0;
        if constexpr (useBP) bpa = (lane ^ mlane) << 2;   // hoisted, 1/gate

        // gather phase: partner values for every pair
        f32x2 pX[NPK], pY[NPK];
        #pragma unroll
        for (int k = 0; k < NPK; ++k) {
            f32x2 px = X[k ^ kreg], py = Y[k ^ kreg];
            if constexpr (kswap) { px = swap2(px); py = swap2(py); }
            if constexpr (useDPP) {
                px.x = xdpp<mlane & 15>(px.x); px.y = xdpp<mlane & 15>(px.y);
                py.x = xdpp<mlane & 15>(py.x); py.y = xdpp<mlane & 15>(py.y);
            } else if constexpr (usePL16) {
                px.x = xpl16<mlane & 31>(px.x, lane); px.y = xpl16<mlane & 31>(px.y, lane);
                py.x = xpl16<mlane & 31>(py.x, lane); py.y = xpl16<mlane & 31>(py.y, lane);
            } else if constexpr (useBP) {
                px.x = xbp(bpa, px.x); px.y = xbp(bpa, px.y);
                py.x = xbp(bpa, py.x); py.y = xbp(bpa, py.y);
            }
            pX[k] = px; pY[k] = py;
        }
        // compute phase: element-wise vector FMA only
        #pragma unroll
        for (int k = 0; k < NPK; ++k) {
            const int vs = __popc(dreg & (2 * k)) & 1;     // compile-time
            const f32x2 scyv = vs ? scyB : scyA;
            const f32x2 pcxv = vs ? pcxB : pcxA;
            const f32x2 sX = X[k], sY = Y[k];
            f32x2 nX = sX * g00xv;
            nX -= scyv * sY;
            nX += pcxv * pX[k];
            nX -= g01yv * pY[k];
            f32x2 nY = sY * g00xv;
            nY += scyv * sX;
            nY += pcxv * pY[k];
            nY += g01yv * pX[k];
            X[k] = nX; Y[k] = nY;
        }
    }
}

template <int GI>
__device__ __forceinline__ void gates_from(f32x2 (&X)[NPK], f32x2 (&Y)[NPK],
                                           float g00x_r, float g00y_r,
                                           float g01x_r, float g01y_r, int lane) {
    if constexpr (GI < NL * NQ) {
        apply_gate<GI>(X, Y, g00x_r, g00y_r, g01x_r, g01y_r, lane);
        gates_from<GI + 1>(X, Y, g00x_r, g00y_r, g01x_r, g01y_r, lane);
    }
}

// ---------------------------------------------------------------------------
// 4 samples per 256-thread block; each wave owns one sample independently
// (no barriers, no LDS buffers).
// ---------------------------------------------------------------------------
__global__ __launch_bounds__(64 * SPB) void qnn_kernel(const float* __restrict__ x,
                                                       const float* __restrict__ wts,
                                                       float* __restrict__ out) {
    const int b    = blockIdx.x * SPB + (threadIdx.x >> 6);
    const int lane = threadIdx.x & 63;

    // ---- gate coefficients: lane gi computes Rot gate gi (branchless clamp)
    const int gidx = (lane < NL * NQ) ? lane : 0;
    float g00x_r, g00y_r, g01x_r, g01y_r;
    {
        float phi = wts[gidx * 3 + 0];
        float th  = wts[gidx * 3 + 1];
        float om  = wts[gidx * 3 + 2];
        float st_, ct_; sincos_tiny(0.5f * th, &st_, &ct_);
        float sp,  cp;  sincos_tiny(0.5f * (phi + om), &sp, &cp);
        float sm,  cm;  sincos_tiny(0.5f * (phi - om), &sm, &cm);
        g00x_r =  cp * ct_;  g00y_r = -sp * ct_;   // m00 = e^{-i(phi+om)/2} cos
        g01x_r = -cm * st_;  g01y_r = -sm * st_;   // m01 = -e^{+i(phi-om)/2} sin
    }

    // ---- RX encoding angles: lane w computes sincos(pi*x_w/2), a in [0,pi/2]
    float myc, mys;
    {
        const int w = (lane < NQ) ? lane : 0;
        sincos_q(1.57079632679f * x[b * NQ + w], &mys, &myc);
    }

    // ---- fold layer-0 Rot into product factors, per-lane via readlane
    f32x2 u0[NQ], u1[NQ];
    #pragma unroll
    for (int w = 0; w < NQ; ++w) {
        const float a  = rdl(g00x_r, w), bb = rdl(g00y_r, w);
        const float c  = rdl(g01x_r, w), dd = rdl(g01y_r, w);
        const float cw = rdl(myc, w),    sw = rdl(mys, w);
        const int p = NQ - 1 - w;
        u0[p].x =  a * cw + dd * sw;
        u0[p].y = bb * cw -  c * sw;
        u1[p].x = -c * cw - bb * sw;
        u1[p].y = dd * cw -  a * sw;
    }

    // ---- init: product state  a[q] = prod_p u'_{p, bit_p(q)}, packed SoA
    f32x2 PL = (lane & 1) ? u1[0] : u0[0];
    #pragma unroll
    for (int p = 1; p < 6; ++p)
        PL = cmul(PL, ((lane >> p) & 1) ? u1[p] : u0[p]);

    f32x2 t67[4], r89[4];
    #pragma unroll
    for (int a = 0; a < 4; ++a) {
        f32x2 r = cmul((a & 1) ? u1[6] : u0[6], (a & 2) ? u1[7] : u0[7]);
        t67[a] = cmul(PL, r);
        r89[a] = cmul((a & 1) ? u1[8] : u0[8], (a & 2) ? u1[9] : u0[9]);
    }

    f32x2 X[NPK], Y[NPK];
    #pragma unroll
    for (int k = 0; k < NPK; ++k) {
        const int j0 = 2 * k, j1 = 2 * k + 1;
        f32x2 a0 = cmul(t67[j0 & 3], r89[j0 >> 2]);
        f32x2 a1 = cmul(t67[j1 & 3], r89[j1 >> 2]);
        X[k].x = a0.x; X[k].y = a1.x;
        Y[k].x = a0.y; Y[k].y = a1.y;
    }

    // ---- Rot gates (layers 1..3) in stored space; CNOT rings are free.
    gates_from<NQ>(X, Y, g00x_r, g00y_r, g01x_r, g01y_r, lane);

    // ---- <Z>: sign(q) = (-1)^parity(sgn & q)
    const int sl = __popc(MK.sgn & 63 & lane) & 1;
    const float bsign = sl ? -1.f : 1.f;
    const int sb = (MK.sgn >> 6) & 15;
    float acc = 0.f;
    #pragma unroll
    for (int k = 0; k < NPK; ++k) {
        const int c0 = __popc(sb & (2 * k)) & 1;           // compile-time
        const int c1 = c0 ^ (sb & 1);
        f32x2 mag = X[k] * X[k] + Y[k] * Y[k];
        acc = fmaf(mag.x, c0 ? -bsign : bsign, acc);
        acc = fmaf(mag.y, c1 ? -bsign : bsign, acc);
    }
    // ---- wave reduction: DPP for 1,2,4,8; permlane16 for 16; bpermute for 32
    acc += xdpp<1>(acc);
    acc += xdpp<2>(acc);
    acc += xdpp<4>(acc);
    acc += xdpp<8>(acc);
    acc += xpl16<16>(acc, lane);
    acc += xbp((lane ^ 32) << 2, acc);
    if (lane == 0) out[b] = acc;
}

extern "C" void kernel_launch(void* const* d_in, const int* in_sizes, int n_in,
                              void* d_out, int out_size, void* d_ws, size_t ws_size,
                              hipStream_t stream) {
    (void)n_in; (void)d_ws; (void)ws_size; (void)out_size;
    const float* x   = (const float*)d_in[0];   // (2048, 10) float32
    const float* wts = (const float*)d_in[1];   // (4, 10, 3) float32
    float* out = (float*)d_out;                 // (2048, 1) float32
    int B = in_sizes[0] / NQ;                   // 2048
    qnn_kernel<<<B / SPB, 64 * SPB, 0, stream>>>(x, wts, out);
}

// Round 14
// 18.058 us; speedup vs baseline: 1.1494x; 1.1494x over previous
//
#include <hip/hip_runtime.h>
#include <math.h>

#define NQ   10
#define NL   4
#define NREG 16   // 1024 amplitudes / 64 lanes
#define NPK  8    // 8 f32x2 pairs (SoA packing of adjacent j)

typedef float f32x2 __attribute__((ext_vector_type(2)));

// ---------------------------------------------------------------------------
// Compile-time GF(2) tracking of the CNOT rings.
// stored[q] = amp[L q]; gate on logical bit p pairs {q, q^m}, m = col p of
// L^-1; logical bit value = parity(row_p(L) & q). Layer 0 folded into init.
// Layer-3 gates commuting with <Z> (parity(sgn&m)==0) are deleted.
// ---------------------------------------------------------------------------
struct MaskTab { int m[NL * NQ]; int d[NL * NQ]; bool keep[NL * NQ]; int sgn; bool ok; };

constexpr MaskTab make_masks() {
    MaskTab t{};
    int L[NQ] = {}, Li[NQ] = {};
    for (int p = 0; p < NQ; ++p) { L[p] = 1 << p; Li[p] = 1 << p; }
    for (int l = 0; l < NL; ++l) {
        for (int w = 0; w < NQ; ++w) {
            int p = NQ - 1 - w;
            int mm = 0;
            for (int tt = 0; tt < NQ; ++tt) mm |= ((Li[tt] >> p) & 1) << tt;
            t.m[l * NQ + w] = mm;
            t.d[l * NQ + w] = L[p];
        }
        int r = (l % (NQ - 1)) + 1;
        for (int w = 0; w < NQ; ++w) {           // L <- P_l^-1 L
            int pc = NQ - 1 - w;
            int tq = w + r; if (tq >= NQ) tq -= NQ;
            int pt = NQ - 1 - tq;
            L[pt] ^= L[pc];
        }
        for (int w = 0; w < NQ; ++w) {           // Li <- Li P_l
            int pc = NQ - 1 - w;
            int tq = w + r; if (tq >= NQ) tq -= NQ;
            int pt = NQ - 1 - tq;
            for (int p = 0; p < NQ; ++p)
                Li[p] ^= ((Li[p] >> pt) & 1) << pc;
        }
    }
    t.sgn = L[0];
    for (int gi = 0; gi < NL * NQ; ++gi) {
        if (gi < NQ) { t.keep[gi] = false; continue; }            // layer 0 folded
        if (gi < (NL - 1) * NQ) { t.keep[gi] = true; continue; }
        t.keep[gi] = (__builtin_popcount((unsigned)(t.sgn & t.m[gi])) & 1) != 0;
    }
    bool ok = true;
    for (int p = 0; p < NQ; ++p) {
        int row = 0;
        for (int k = 0; k < NQ; ++k)
            if ((L[p] >> k) & 1) row ^= Li[k];
        if (row != (1 << p)) ok = false;
    }
    t.ok = ok;
    return t;
}

static constexpr MaskTab MK = make_masks();
static_assert(MK.ok, "GF(2) inverse check failed");

// ---------------------------------------------------------------------------
// Cross-lane xor-exchange, routed by compile-time mask (R7/R11 optimum):
//   bits 0-3 only  -> 1-2 v_mov_dpp   (VALU pipe)
//   bits 0-4       -> 1 ds_swizzle    (DS pipe, xor BitMode)
//   bit 5 set      -> 1 ds_bpermute   (DS pipe, hoisted addr)
// ---------------------------------------------------------------------------
constexpr int dpp_direct(int m) {
    return m == 1 ? 0xB1 : m == 2 ? 0x4E : m == 3 ? 0x1B :
           m == 7 ? 0x141 : m == 8 ? 0x128 : m == 15 ? 0x140 : 0;
}
constexpr int dpp1(int m) {
    return dpp_direct(m)      ? dpp_direct(m) :
           dpp_direct(m ^ 8)  ? 0x128 :
           dpp_direct(m ^ 15) ? 0x140 : 0x141;
}
constexpr int dpp2(int m) {
    return dpp_direct(m)      ? 0 :
           dpp_direct(m ^ 8)  ? dpp_direct(m ^ 8) :
           dpp_direct(m ^ 15) ? dpp_direct(m ^ 15) : dpp_direct(m ^ 7);
}

template <int M>
__device__ __forceinline__ float xdpp(float v) {
    static_assert((M & ~15) == 0 && M != 0, "dpp mask must be 4-bit");
    int u = __builtin_amdgcn_mov_dpp(__float_as_int(v), dpp1(M), 0xF, 0xF, true);
    if constexpr (dpp2(M) != 0)
        u = __builtin_amdgcn_mov_dpp(u, dpp2(M), 0xF, 0xF, true);
    return __int_as_float(u);
}
template <int M>
__device__ __forceinline__ float xswz(float v) {
    static_assert((M & ~31) == 0 && M != 0, "swizzle mask must be 5-bit");
    return __int_as_float(__builtin_amdgcn_ds_swizzle(__float_as_int(v), (M << 10) | 0x1F));
}
__device__ __forceinline__ float xbp(int bpa, float v) {
    return __int_as_float(__builtin_amdgcn_ds_bpermute(bpa, __float_as_int(v)));
}

__device__ __forceinline__ float fxor(float a, unsigned s) {
    return __uint_as_float(__float_as_uint(a) ^ s);
}
__device__ __forceinline__ f32x2 bc2(float v) { f32x2 r; r.x = v; r.y = v; return r; }
__device__ __forceinline__ f32x2 swap2(f32x2 v) { f32x2 r; r.x = v.y; r.y = v.x; return r; }
__device__ __forceinline__ f32x2 cmul(f32x2 a, f32x2 b) {
    f32x2 r;
    r.x = a.x * b.x - a.y * b.y;
    r.y = a.x * b.y + a.y * b.x;
    return r;
}
__device__ __forceinline__ float rdl(float v, int l) {
    return __uint_as_float((unsigned)__builtin_amdgcn_readlane((int)__float_as_uint(v), l));
}

// ---------------------------------------------------------------------------
// Polynomial sincos (no library calls, no branches).
// sincos_tiny: |a| < ~0.5 (gate angles < 0.06): err < 2e-9.
// sincos_q:    a in [0, pi/2] (RX encoding): half-angle + deg-7/8, err ~3e-7.
// ---------------------------------------------------------------------------
__device__ __forceinline__ void sincos_tiny(float a, float* s, float* c) {
    float t = a * a;
    *s = a * fmaf(t, fmaf(t, 8.3333333e-3f, -0.16666667f), 1.0f);
    *c = fmaf(t, fmaf(t, fmaf(t, -1.3888889e-3f, 4.1666668e-2f), -0.5f), 1.0f);
}
__device__ __forceinline__ void sincos_q(float a, float* s, float* c) {
    float h = 0.5f * a, u = h * h;
    float sh = h * fmaf(u, fmaf(u, fmaf(u, -1.9841270e-4f, 8.3333333e-3f), -0.16666667f), 1.0f);
    float ch = fmaf(u, fmaf(u, fmaf(u, fmaf(u, 2.4801587e-5f, -1.3888889e-3f),
                                    4.1666668e-2f), -0.5f), 1.0f);
    *s = 2.0f * sh * ch;
    *c = fmaf(-2.0f * sh, sh, 1.0f);
}

// ---------------------------------------------------------------------------
// One gate on SoA state: X[k]/Y[k] hold re/im of amplitudes j=2k, 2k+1.
// Compute phase is pure element-wise vector FMA (v_pk_fma_f32):
//   nX = g00x*sX - scyv*sY + pcxv*pX - g01y*pY
//   nY = g00x*sY + scyv*sX + pcxv*pY + g01y*pX
// ---------------------------------------------------------------------------
template <int GI>
__device__ __forceinline__ void apply_gate(f32x2 (&X)[NPK], f32x2 (&Y)[NPK],
                                           float g00x_r, float g00y_r,
                                           float g01x_r, float g01y_r, int lane) {
    if constexpr (MK.keep[GI]) {
        constexpr int m     = MK.m[GI];
        constexpr int d     = MK.d[GI];
        constexpr int mreg  = (m >> 6) & 15;
        constexpr int mlane = m & 63;
        constexpr int dreg  = (d >> 6) & 15;
        constexpr int dlane = d & 63;
        constexpr int  kreg  = mreg >> 1;          // pair-index xor
        constexpr bool kswap = (mreg & 1) != 0;    // within-pair half swap
        constexpr bool useDPP = (mlane != 0) && ((mlane & 48) == 0);
        constexpr bool useSWZ = (mlane != 0) && !useDPP && ((mlane & 32) == 0);
        constexpr bool useBP  = (mlane != 0) && !useDPP && !useSWZ;

        const float g00x = rdl(g00x_r, GI);        // uniform broadcast, no DS
        const float g00y = rdl(g00y_r, GI);
        const float g01x = rdl(g01x_r, GI);
        const float g01y = rdl(g01y_r, GI);

        const int bl = __popc(dlane & lane) & 1;   // lane part of bit value
        const unsigned s0 = (unsigned)bl << 31;
        const float scy0 = fxor(g00y, s0), pcx0 = fxor(g01x, s0);
        const float scy1 = fxor(scy0, 0x80000000u), pcx1 = fxor(pcx0, 0x80000000u);

        // per-pair sign-vector variants (A: v(2k)=0, B: v(2k)=1)
        f32x2 scyA, scyB, pcxA, pcxB;
        if constexpr (dreg & 1) {                   // alternating within pair
            scyA.x = scy0; scyA.y = scy1;  scyB.x = scy1; scyB.y = scy0;
            pcxA.x = pcx0; pcxA.y = pcx1;  pcxB.x = pcx1; pcxB.y = pcx0;
        } else {                                    // uniform within pair
            scyA = bc2(scy0); scyB = bc2(scy1);
            pcxA = bc2(pcx0); pcxB = bc2(pcx1);
        }
        const f32x2 g00xv = bc2(g00x);
        const f32x2 g01yv = bc2(g01y);

        [[maybe_unused]] int bpa = 0;
        if constexpr (useBP) bpa = (lane ^ mlane) << 2;   // hoisted, 1/gate

        // gather phase: partner values for every pair (batched DS issue —
        // needs the VGPR headroom granted by __launch_bounds__(64, 2))
        f32x2 pX[NPK], pY[NPK];
        #pragma unroll
        for (int k = 0; k < NPK; ++k) {
            f32x2 px = X[k ^ kreg], py = Y[k ^ kreg];
            if constexpr (kswap) { px = swap2(px); py = swap2(py); }
            if constexpr (useDPP) {
                px.x = xdpp<mlane & 15>(px.x); px.y = xdpp<mlane & 15>(px.y);
                py.x = xdpp<mlane & 15>(py.x); py.y = xdpp<mlane & 15>(py.y);
            } else if constexpr (useSWZ) {
                px.x = xswz<mlane & 31>(px.x); px.y = xswz<mlane & 31>(px.y);
                py.x = xswz<mlane & 31>(py.x); py.y = xswz<mlane & 31>(py.y);
            } else if constexpr (useBP) {
                px.x = xbp(bpa, px.x); px.y = xbp(bpa, px.y);
                py.x = xbp(bpa, py.x); py.y = xbp(bpa, py.y);
            }
            pX[k] = px; pY[k] = py;
        }
        // compute phase: element-wise vector FMA only
        #pragma unroll
        for (int k = 0; k < NPK; ++k) {
            const int vs = __popc(dreg & (2 * k)) & 1;     // compile-time
            const f32x2 scyv = vs ? scyB : scyA;
            const f32x2 pcxv = vs ? pcxB : pcxA;
            const f32x2 sX = X[k], sY = Y[k];
            f32x2 nX = sX * g00xv;
            nX -= scyv * sY;
            nX += pcxv * pX[k];
            nX -= g01yv * pY[k];
            f32x2 nY = sY * g00xv;
            nY += scyv * sX;
            nY += pcxv * pY[k];
            nY += g01yv * pX[k];
            X[k] = nX; Y[k] = nY;
        }
    }
}

template <int GI>
__device__ __forceinline__ void gates_from(f32x2 (&X)[NPK], f32x2 (&Y)[NPK],
                                           float g00x_r, float g00y_r,
                                           float g01x_r, float g01y_r, int lane) {
    if constexpr (GI < NL * NQ) {
        apply_gate<GI>(X, Y, g00x_r, g00y_r, g01x_r, g01y_r, lane);
        gates_from<GI + 1>(X, Y, g00x_r, g00y_r, g01x_r, g01y_r, lane);
    }
}

// ---------------------------------------------------------------------------
// One sample per wave. SoA state in VGPRs. No LDS buffers, no barriers.
// __launch_bounds__(64, 2): grid supplies only 2 waves/SIMD, so request
// exactly that occupancy -> VGPR cap ~256 instead of 64 -> the gather phase
// can hold all partner registers live and batch its DS issues.
// ---------------------------------------------------------------------------
__global__ __launch_bounds__(64, 2) void qnn_kernel(const float* __restrict__ x,
                                                    const float* __restrict__ wts,
                                                    float* __restrict__ out) {
    const int b    = blockIdx.x;
    const int lane = threadIdx.x;

    // ---- gate coefficients: lane gi computes Rot gate gi (branchless clamp)
    const int gidx = (lane < NL * NQ) ? lane : 0;
    float g00x_r, g00y_r, g01x_r, g01y_r;
    {
        float phi = wts[gidx * 3 + 0];
        float th  = wts[gidx * 3 + 1];
        float om  = wts[gidx * 3 + 2];
        float st_, ct_; sincos_tiny(0.5f * th, &st_, &ct_);
        float sp,  cp;  sincos_tiny(0.5f * (phi + om), &sp, &cp);
        float sm,  cm;  sincos_tiny(0.5f * (phi - om), &sm, &cm);
        g00x_r =  cp * ct_;  g00y_r = -sp * ct_;   // m00 = e^{-i(phi+om)/2} cos
        g01x_r = -cm * st_;  g01y_r = -sm * st_;   // m01 = -e^{+i(phi-om)/2} sin
    }

    // ---- RX encoding angles: lane w computes sincos(pi*x_w/2), a in [0,pi/2]
    float myc, mys;
    {
        const int w = (lane < NQ) ? lane : 0;
        sincos_q(1.57079632679f * x[b * NQ + w], &mys, &myc);
    }

    // ---- fold layer-0 Rot into product factors, per-lane via readlane
    f32x2 u0[NQ], u1[NQ];
    #pragma unroll
    for (int w = 0; w < NQ; ++w) {
        const float a  = rdl(g00x_r, w), bb = rdl(g00y_r, w);
        const float c  = rdl(g01x_r, w), dd = rdl(g01y_r, w);
        const float cw = rdl(myc, w),    sw = rdl(mys, w);
        const int p = NQ - 1 - w;
        u0[p].x =  a * cw + dd * sw;
        u0[p].y = bb * cw -  c * sw;
        u1[p].x = -c * cw - bb * sw;
        u1[p].y = dd * cw -  a * sw;
    }

    // ---- init: product state  a[q] = prod_p u'_{p, bit_p(q)}, packed SoA
    f32x2 PL = (lane & 1) ? u1[0] : u0[0];
    #pragma unroll
    for (int p = 1; p < 6; ++p)
        PL = cmul(PL, ((lane >> p) & 1) ? u1[p] : u0[p]);

    f32x2 t67[4], r89[4];
    #pragma unroll
    for (int a = 0; a < 4; ++a) {
        f32x2 r = cmul((a & 1) ? u1[6] : u0[6], (a & 2) ? u1[7] : u0[7]);
        t67[a] = cmul(PL, r);
        r89[a] = cmul((a & 1) ? u1[8] : u0[8], (a & 2) ? u1[9] : u0[9]);
    }

    f32x2 X[NPK], Y[NPK];
    #pragma unroll
    for (int k = 0; k < NPK; ++k) {
        const int j0 = 2 * k, j1 = 2 * k + 1;
        f32x2 a0 = cmul(t67[j0 & 3], r89[j0 >> 2]);
        f32x2 a1 = cmul(t67[j1 & 3], r89[j1 >> 2]);
        X[k].x = a0.x; X[k].y = a1.x;
        Y[k].x = a0.y; Y[k].y = a1.y;
    }

    // ---- Rot gates (layers 1..3) in stored space; CNOT rings are free.
    gates_from<NQ>(X, Y, g00x_r, g00y_r, g01x_r, g01y_r, lane);

    // ---- <Z>: sign(q) = (-1)^parity(sgn & q)
    const int sl = __popc(MK.sgn & 63 & lane) & 1;
    const float bsign = sl ? -1.f : 1.f;
    const int sb = (MK.sgn >> 6) & 15;
    float acc = 0.f;
    #pragma unroll
    for (int k = 0; k < NPK; ++k) {
        const int c0 = __popc(sb & (2 * k)) & 1;           // compile-time
        const int c1 = c0 ^ (sb & 1);
        f32x2 mag = X[k] * X[k] + Y[k] * Y[k];
        acc = fmaf(mag.x, c0 ? -bsign : bsign, acc);
        acc = fmaf(mag.y, c1 ? -bsign : bsign, acc);
    }
    // ---- wave reduction: DPP for 1,2,4,8; swizzle for 16; bpermute for 32
    acc += xdpp<1>(acc);
    acc += xdpp<2>(acc);
    acc += xdpp<4>(acc);
    acc += xdpp<8>(acc);
    acc += xswz<16>(acc);
    acc += xbp((lane ^ 32) << 2, acc);
    if (lane == 0) out[b] = acc;
}

extern "C" void kernel_launch(void* const* d_in, const int* in_sizes, int n_in,
                              void* d_out, int out_size, void* d_ws, size_t ws_size,
                              hipStream_t stream) {
    (void)n_in; (void)d_ws; (void)ws_size; (void)out_size;
    const float* x   = (const float*)d_in[0];   // (2048, 10) float32
    const float* wts = (const float*)d_in[1];   // (4, 10, 3) float32
    float* out = (float*)d_out;                 // (2048, 1) float32
    int B = in_sizes[0] / NQ;                   // 2048
    qnn_kernel<<<B, 64, 0, stream>>>(x, wts, out);
}

// Round 15
// 17.558 us; speedup vs baseline: 1.1821x; 1.0285x over previous
//
#include <hip/hip_runtime.h>
#include <math.h>

#define NQ   10
#define NL   4
#define NPK  8    // 8 f32x2 pairs (SoA packing of adjacent j)

typedef float f32x2 __attribute__((ext_vector_type(2)));

// ---------------------------------------------------------------------------
// Compile-time GF(2) tracking of the CNOT rings.
// stored[q] = amp[L q]; gate on logical bit p pairs {q, q^m}, m = col p of
// L^-1; logical bit value = parity(row_p(L) & q). Layer 0 folded into init.
// Layer-3 gates commuting with <Z> (parity(sgn&m)==0) are deleted.
// ---------------------------------------------------------------------------
struct MaskTab { int m[NL * NQ]; int d[NL * NQ]; bool keep[NL * NQ]; int sgn; bool ok; };

constexpr MaskTab make_masks() {
    MaskTab t{};
    int L[NQ] = {}, Li[NQ] = {};
    for (int p = 0; p < NQ; ++p) { L[p] = 1 << p; Li[p] = 1 << p; }
    for (int l = 0; l < NL; ++l) {
        for (int w = 0; w < NQ; ++w) {
            int p = NQ - 1 - w;
            int mm = 0;
            for (int tt = 0; tt < NQ; ++tt) mm |= ((Li[tt] >> p) & 1) << tt;
            t.m[l * NQ + w] = mm;
            t.d[l * NQ + w] = L[p];
        }
        int r = (l % (NQ - 1)) + 1;
        for (int w = 0; w < NQ; ++w) {           // L <- P_l^-1 L
            int pc = NQ - 1 - w;
            int tq = w + r; if (tq >= NQ) tq -= NQ;
            int pt = NQ - 1 - tq;
            L[pt] ^= L[pc];
        }
        for (int w = 0; w < NQ; ++w) {           // Li <- Li P_l
            int pc = NQ - 1 - w;
            int tq = w + r; if (tq >= NQ) tq -= NQ;
            int pt = NQ - 1 - tq;
            for (int p = 0; p < NQ; ++p)
                Li[p] ^= ((Li[p] >> pt) & 1) << pc;
        }
    }
    t.sgn = L[0];
    for (int gi = 0; gi < NL * NQ; ++gi) {
        if (gi < NQ) { t.keep[gi] = false; continue; }            // layer 0 folded
        if (gi < (NL - 1) * NQ) { t.keep[gi] = true; continue; }
        t.keep[gi] = (__builtin_popcount((unsigned)(t.sgn & t.m[gi])) & 1) != 0;
    }
    bool ok = true;
    for (int p = 0; p < NQ; ++p) {
        int row = 0;
        for (int k = 0; k < NQ; ++k)
            if ((L[p] >> k) & 1) row ^= Li[k];
        if (row != (1 << p)) ok = false;
    }
    t.ok = ok;
    return t;
}

static constexpr MaskTab MK = make_masks();
static_assert(MK.ok, "GF(2) inverse check failed");

// ---------------------------------------------------------------------------
// GF(2) 10x10 matrix utilities (columns as 10-bit words) + basis-change plan.
// T remaps stored indices (one exact LDS permute after init); masks m'=T m,
// d'/sgn' via T^-T. Greedy: map the 9 costliest independent masks onto the
// cheap targets {e6..e9 (free), e0..e3 (DPP), e4 (swizzle)}.
// ---------------------------------------------------------------------------
struct Mat { unsigned c[10]; };

constexpr unsigned mv(const Mat& M, unsigned v) {
    unsigned r = 0;
    for (int i = 0; i < 10; ++i) if ((v >> i) & 1u) r ^= M.c[i];
    return r;
}
constexpr bool minvert(const Mat& A, Mat* out) {
    unsigned rowA[10] = {}, rowI[10] = {};
    for (int r = 0; r < 10; ++r) {
        unsigned ra = 0;
        for (int cc = 0; cc < 10; ++cc) ra |= ((A.c[cc] >> r) & 1u) << cc;
        rowA[r] = ra; rowI[r] = 1u << r;
    }
    for (int col = 0; col < 10; ++col) {
        int piv = -1;
        for (int r = col; r < 10; ++r) if ((rowA[r] >> col) & 1u) { piv = r; break; }
        if (piv < 0) return false;
        unsigned ta = rowA[col]; rowA[col] = rowA[piv]; rowA[piv] = ta;
        unsigned ti = rowI[col]; rowI[col] = rowI[piv]; rowI[piv] = ti;
        for (int r = 0; r < 10; ++r)
            if (r != col && ((rowA[r] >> col) & 1u)) { rowA[r] ^= rowA[col]; rowI[r] ^= rowI[col]; }
    }
    for (int cc = 0; cc < 10; ++cc) {
        unsigned cv = 0;
        for (int r = 0; r < 10; ++r) cv |= ((rowI[r] >> cc) & 1u) << r;
        out->c[cc] = cv;
    }
    return true;
}
constexpr int xcost(unsigned m) {
    unsigned ml = m & 63u;
    if (ml == 0) return 0;          // register-only exchange: free
    if ((ml & 48u) == 0) return 1;  // DPP
    if ((ml & 32u) == 0) return 3;  // ds_swizzle
    return 4;                       // ds_bpermute
}

struct Plan { Mat T, Ti; bool useT; int m[NL * NQ], d[NL * NQ], sgn; bool ok; };

constexpr Plan make_plan() {
    Plan P{};
    P.ok = true;
    // distinct kept masks, weight = summed current cost
    unsigned dm[NL * NQ] = {}; int dmc[NL * NQ] = {}; int ndm = 0;
    for (int gi = 0; gi < NL * NQ; ++gi) {
        if (!MK.keep[gi]) continue;
        unsigned m = (unsigned)MK.m[gi];
        int f = -1;
        for (int i = 0; i < ndm; ++i) if (dm[i] == m) { f = i; break; }
        if (f < 0) { dm[ndm] = m; dmc[ndm] = xcost(m); ++ndm; }
        else dmc[f] += xcost(m);
    }
    for (int i = 1; i < ndm; ++i) {            // insertion sort by weight desc
        unsigned vm = dm[i]; int vc = dmc[i]; int j = i;
        while (j > 0 && dmc[j - 1] < vc) { dm[j] = dm[j - 1]; dmc[j] = dmc[j - 1]; --j; }
        dm[j] = vm; dmc[j] = vc;
    }
    // greedy independent set (up to 9)
    unsigned sel[10] = {}; int nsel = 0;
    unsigned gb[10] = {};
    for (int i = 0; i < ndm && nsel < 9; ++i) {
        unsigned r = dm[i];
        for (int b = 9; b >= 0; --b) if (((r >> b) & 1u) && gb[b]) r ^= gb[b];
        if (r == 0) continue;
        int lb = 0;
        for (int b = 9; b >= 0; --b) if ((r >> b) & 1u) { lb = b; break; }
        gb[lb] = r;
        sel[nsel++] = dm[i];
    }
    // complete rank with unit vectors
    unsigned comp[10] = {}; int ncomp = 0;
    for (int e = 0; e < 10 && nsel + ncomp < 10; ++e) {
        unsigned r = 1u << e;
        for (int b = 9; b >= 0; --b) if (((r >> b) & 1u) && gb[b]) r ^= gb[b];
        if (r == 0) continue;
        int lb = 0;
        for (int b = 9; b >= 0; --b) if ((r >> b) & 1u) { lb = b; break; }
        gb[lb] = r;
        comp[ncomp++] = 1u << e;
    }
    if (nsel + ncomp != 10) { P.ok = false; return P; }
    const unsigned tord[10] = {64, 128, 256, 512, 1, 2, 4, 8, 16, 32};
    Mat S{}, Tt{};
    for (int i = 0; i < 10; ++i) {
        S.c[i]  = (i < nsel) ? sel[i] : comp[i - nsel];
        Tt.c[i] = tord[i];
    }
    Mat Sinv{};
    if (!minvert(S, &Sinv)) { P.ok = false; return P; }
    for (int i = 0; i < 10; ++i) P.T.c[i] = mv(Tt, Sinv.c[i]);
    if (!minvert(P.T, &P.Ti)) { P.ok = false; return P; }
    for (int i = 0; i < 10; ++i) if (mv(P.T, P.Ti.c[i]) != (1u << i)) P.ok = false;
    // global cost: use T only if it beats identity by more than the pass cost
    int cid = 0, cT = 0;
    for (int gi = 0; gi < NL * NQ; ++gi) {
        if (!MK.keep[gi]) continue;
        cid += xcost((unsigned)MK.m[gi]);
        cT  += xcost(mv(P.T, (unsigned)MK.m[gi]));
    }
    P.useT = (cT + 8 < cid);                   // permute pass ~= 2 bp-gates
    for (int gi = 0; gi < NL * NQ; ++gi) {
        if (P.useT) {
            P.m[gi] = (int)mv(P.T, (unsigned)MK.m[gi]);
            unsigned dd = 0;
            for (int i = 0; i < 10; ++i)
                dd |= (unsigned)(__builtin_popcount((unsigned)MK.d[gi] & P.Ti.c[i]) & 1) << i;
            P.d[gi] = (int)dd;
        } else { P.m[gi] = MK.m[gi]; P.d[gi] = MK.d[gi]; }
    }
    if (P.useT) {
        unsigned ss = 0;
        for (int i = 0; i < 10; ++i)
            ss |= (unsigned)(__builtin_popcount((unsigned)MK.sgn & P.Ti.c[i]) & 1) << i;
        P.sgn = (int)ss;
    } else P.sgn = MK.sgn;
    return P;
}
static constexpr Plan PLN = make_plan();
static_assert(PLN.ok, "basis plan failed");

constexpr unsigned kconstj(int j) {            // reg-bit part of Ti*q'
    unsigned r = 0;
    for (int t = 0; t < 4; ++t) if ((j >> t) & 1) r ^= PLN.Ti.c[6 + t];
    return r;
}

// ---------------------------------------------------------------------------
// Cross-lane xor-exchange, routed by compile-time mask (R7/R11 optimum):
//   bits 0-3 only  -> 1-2 v_mov_dpp   (VALU pipe)
//   bits 0-4       -> 1 ds_swizzle    (DS pipe, xor BitMode)
//   bit 5 set      -> 1 ds_bpermute   (DS pipe, hoisted addr)
// ---------------------------------------------------------------------------
constexpr int dpp_direct(int m) {
    return m == 1 ? 0xB1 : m == 2 ? 0x4E : m == 3 ? 0x1B :
           m == 7 ? 0x141 : m == 8 ? 0x128 : m == 15 ? 0x140 : 0;
}
constexpr int dpp1(int m) {
    return dpp_direct(m)      ? dpp_direct(m) :
           dpp_direct(m ^ 8)  ? 0x128 :
           dpp_direct(m ^ 15) ? 0x140 : 0x141;
}
constexpr int dpp2(int m) {
    return dpp_direct(m)      ? 0 :
           dpp_direct(m ^ 8)  ? dpp_direct(m ^ 8) :
           dpp_direct(m ^ 15) ? dpp_direct(m ^ 15) : dpp_direct(m ^ 7);
}

template <int M>
__device__ __forceinline__ float xdpp(float v) {
    static_assert((M & ~15) == 0 && M != 0, "dpp mask must be 4-bit");
    int u = __builtin_amdgcn_mov_dpp(__float_as_int(v), dpp1(M), 0xF, 0xF, true);
    if constexpr (dpp2(M) != 0)
        u = __builtin_amdgcn_mov_dpp(u, dpp2(M), 0xF, 0xF, true);
    return __int_as_float(u);
}
template <int M>
__device__ __forceinline__ float xswz(float v) {
    static_assert((M & ~31) == 0 && M != 0, "swizzle mask must be 5-bit");
    return __int_as_float(__builtin_amdgcn_ds_swizzle(__float_as_int(v), (M << 10) | 0x1F));
}
__device__ __forceinline__ float xbp(int bpa, float v) {
    return __int_as_float(__builtin_amdgcn_ds_bpermute(bpa, __float_as_int(v)));
}

__device__ __forceinline__ float fxor(float a, unsigned s) {
    return __uint_as_float(__float_as_uint(a) ^ s);
}
__device__ __forceinline__ f32x2 bc2(float v) { f32x2 r; r.x = v; r.y = v; return r; }
__device__ __forceinline__ f32x2 swap2(f32x2 v) { f32x2 r; r.x = v.y; r.y = v.x; return r; }
__device__ __forceinline__ f32x2 cmul(f32x2 a, f32x2 b) {
    f32x2 r;
    r.x = a.x * b.x - a.y * b.y;
    r.y = a.x * b.y + a.y * b.x;
    return r;
}
__device__ __forceinline__ float rdl(float v, int l) {
    return __uint_as_float((unsigned)__builtin_amdgcn_readlane((int)__float_as_uint(v), l));
}

// ---------------------------------------------------------------------------
// Polynomial sincos (no library calls, no branches).
// ---------------------------------------------------------------------------
__device__ __forceinline__ void sincos_tiny(float a, float* s, float* c) {
    float t = a * a;
    *s = a * fmaf(t, fmaf(t, 8.3333333e-3f, -0.16666667f), 1.0f);
    *c = fmaf(t, fmaf(t, fmaf(t, -1.3888889e-3f, 4.1666668e-2f), -0.5f), 1.0f);
}
__device__ __forceinline__ void sincos_q(float a, float* s, float* c) {
    float h = 0.5f * a, u = h * h;
    float sh = h * fmaf(u, fmaf(u, fmaf(u, -1.9841270e-4f, 8.3333333e-3f), -0.16666667f), 1.0f);
    float ch = fmaf(u, fmaf(u, fmaf(u, fmaf(u, 2.4801587e-5f, -1.3888889e-3f),
                                    4.1666668e-2f), -0.5f), 1.0f);
    *s = 2.0f * sh * ch;
    *c = fmaf(-2.0f * sh, sh, 1.0f);
}

// ---------------------------------------------------------------------------
// One gate on SoA state (masks/d from the basis plan PLN).
// ---------------------------------------------------------------------------
template <int GI>
__device__ __forceinline__ void apply_gate(f32x2 (&X)[NPK], f32x2 (&Y)[NPK],
                                           float g00x_r, float g00y_r,
                                           float g01x_r, float g01y_r, int lane) {
    if constexpr (MK.keep[GI]) {
        constexpr int m     = PLN.m[GI];
        constexpr int d     = PLN.d[GI];
        constexpr int mreg  = (m >> 6) & 15;
        constexpr int mlane = m & 63;
        constexpr int dreg  = (d >> 6) & 15;
        constexpr int dlane = d & 63;
        constexpr int  kreg  = mreg >> 1;
        constexpr bool kswap = (mreg & 1) != 0;
        constexpr bool useDPP = (mlane != 0) && ((mlane & 48) == 0);
        constexpr bool useSWZ = (mlane != 0) && !useDPP && ((mlane & 32) == 0);
        constexpr bool useBP  = (mlane != 0) && !useDPP && !useSWZ;

        const float g00x = rdl(g00x_r, GI);
        const float g00y = rdl(g00y_r, GI);
        const float g01x = rdl(g01x_r, GI);
        const float g01y = rdl(g01y_r, GI);

        const int bl = __popc(dlane & lane) & 1;
        const unsigned s0 = (unsigned)bl << 31;
        const float scy0 = fxor(g00y, s0), pcx0 = fxor(g01x, s0);
        const float scy1 = fxor(scy0, 0x80000000u), pcx1 = fxor(pcx0, 0x80000000u);

        f32x2 scyA, scyB, pcxA, pcxB;
        if constexpr (dreg & 1) {
            scyA.x = scy0; scyA.y = scy1;  scyB.x = scy1; scyB.y = scy0;
            pcxA.x = pcx0; pcxA.y = pcx1;  pcxB.x = pcx1; pcxB.y = pcx0;
        } else {
            scyA = bc2(scy0); scyB = bc2(scy1);
            pcxA = bc2(pcx0); pcxB = bc2(pcx1);
        }
        const f32x2 g00xv = bc2(g00x);
        const f32x2 g01yv = bc2(g01y);

        [[maybe_unused]] int bpa = 0;
        if constexpr (useBP) bpa = (lane ^ mlane) << 2;

        f32x2 pX[NPK], pY[NPK];
        #pragma unroll
        for (int k = 0; k < NPK; ++k) {
            f32x2 px = X[k ^ kreg], py = Y[k ^ kreg];
            if constexpr (kswap) { px = swap2(px); py = swap2(py); }
            if constexpr (useDPP) {
                px.x = xdpp<mlane & 15>(px.x); px.y = xdpp<mlane & 15>(px.y);
                py.x = xdpp<mlane & 15>(py.x); py.y = xdpp<mlane & 15>(py.y);
            } else if constexpr (useSWZ) {
                px.x = xswz<mlane & 31>(px.x); px.y = xswz<mlane & 31>(px.y);
                py.x = xswz<mlane & 31>(py.x); py.y = xswz<mlane & 31>(py.y);
            } else if constexpr (useBP) {
                px.x = xbp(bpa, px.x); px.y = xbp(bpa, px.y);
                py.x = xbp(bpa, py.x); py.y = xbp(bpa, py.y);
            }
            pX[k] = px; pY[k] = py;
        }
        #pragma unroll
        for (int k = 0; k < NPK; ++k) {
            const int vs = __popc(dreg & (2 * k)) & 1;     // compile-time
            const f32x2 scyv = vs ? scyB : scyA;
            const f32x2 pcxv = vs ? pcxB : pcxA;
            const f32x2 sX = X[k], sY = Y[k];
            f32x2 nX = sX * g00xv;
            nX -= scyv * sY;
            nX += pcxv * pX[k];
            nX -= g01yv * pY[k];
            f32x2 nY = sY * g00xv;
            nY += scyv * sX;
            nY += pcxv * pY[k];
            nY += g01yv * pX[k];
            X[k] = nX; Y[k] = nY;
        }
    }
}

template <int GI>
__device__ __forceinline__ void gates_from(f32x2 (&X)[NPK], f32x2 (&Y)[NPK],
                                           float g00x_r, float g00y_r,
                                           float g01x_r, float g01y_r, int lane) {
    if constexpr (GI < NL * NQ) {
        apply_gate<GI>(X, Y, g00x_r, g00y_r, g01x_r, g01y_r, lane);
        gates_from<GI + 1>(X, Y, g00x_r, g00y_r, g01x_r, g01y_r, lane);
    }
}

// ---------------------------------------------------------------------------
// One sample per wave. SoA state in VGPRs. Optional one-time LDS permutation
// pass (exact) applies the basis change T after init.
// ---------------------------------------------------------------------------
__global__ __launch_bounds__(64, 2) void qnn_kernel(const float* __restrict__ x,
                                                    const float* __restrict__ wts,
                                                    float* __restrict__ out) {
    const int b    = blockIdx.x;
    const int lane = threadIdx.x;

    const int gidx = (lane < NL * NQ) ? lane : 0;
    float g00x_r, g00y_r, g01x_r, g01y_r;
    {
        float phi = wts[gidx * 3 + 0];
        float th  = wts[gidx * 3 + 1];
        float om  = wts[gidx * 3 + 2];
        float st_, ct_; sincos_tiny(0.5f * th, &st_, &ct_);
        float sp,  cp;  sincos_tiny(0.5f * (phi + om), &sp, &cp);
        float sm,  cm;  sincos_tiny(0.5f * (phi - om), &sm, &cm);
        g00x_r =  cp * ct_;  g00y_r = -sp * ct_;
        g01x_r = -cm * st_;  g01y_r = -sm * st_;
    }

    float myc, mys;
    {
        const int w = (lane < NQ) ? lane : 0;
        sincos_q(1.57079632679f * x[b * NQ + w], &mys, &myc);
    }

    f32x2 u0[NQ], u1[NQ];
    #pragma unroll
    for (int w = 0; w < NQ; ++w) {
        const float a  = rdl(g00x_r, w), bb = rdl(g00y_r, w);
        const float c  = rdl(g01x_r, w), dd = rdl(g01y_r, w);
        const float cw = rdl(myc, w),    sw = rdl(mys, w);
        const int p = NQ - 1 - w;
        u0[p].x =  a * cw + dd * sw;
        u0[p].y = bb * cw -  c * sw;
        u1[p].x = -c * cw - bb * sw;
        u1[p].y = dd * cw -  a * sw;
    }

    f32x2 PLn = (lane & 1) ? u1[0] : u0[0];
    #pragma unroll
    for (int p = 1; p < 6; ++p)
        PLn = cmul(PLn, ((lane >> p) & 1) ? u1[p] : u0[p]);

    f32x2 t67[4], r89[4];
    #pragma unroll
    for (int a = 0; a < 4; ++a) {
        f32x2 r = cmul((a & 1) ? u1[6] : u0[6], (a & 2) ? u1[7] : u0[7]);
        t67[a] = cmul(PLn, r);
        r89[a] = cmul((a & 1) ? u1[8] : u0[8], (a & 2) ? u1[9] : u0[9]);
    }

    f32x2 X[NPK], Y[NPK];
    #pragma unroll
    for (int k = 0; k < NPK; ++k) {
        const int j0 = 2 * k, j1 = 2 * k + 1;
        f32x2 a0 = cmul(t67[j0 & 3], r89[j0 >> 2]);
        f32x2 a1 = cmul(t67[j1 & 3], r89[j1 >> 2]);
        X[k].x = a0.x; X[k].y = a1.x;
        Y[k].x = a0.y; Y[k].y = a1.y;
    }

    // ---- one-time basis-change permutation: stored'[q'] = stored[Ti q']
    if constexpr (PLN.useT) {
        __shared__ float lb[2048];                 // (re,im) interleaved, 8 KB
        #pragma unroll
        for (int k = 0; k < NPK; ++k) {
            #pragma unroll
            for (int e = 0; e < 2; ++e) {
                const int q = ((2 * k + e) << 6) | lane;
                lb[2 * q]     = (e ? X[k].y : X[k].x);
                lb[2 * q + 1] = (e ? Y[k].y : Y[k].x);
            }
        }
        __syncthreads();
        unsigned la = 0;
        #pragma unroll
        for (int i = 0; i < 6; ++i)
            la ^= ((lane >> i) & 1) ? PLN.Ti.c[i] : 0u;
        #pragma unroll
        for (int k = 0; k < NPK; ++k) {
            #pragma unroll
            for (int e = 0; e < 2; ++e) {
                const unsigned qs = la ^ kconstj(2 * k + e);   // folds to const xor
                const float re = lb[2 * qs], im = lb[2 * qs + 1];
                if (e) { X[k].y = re; Y[k].y = im; }
                else   { X[k].x = re; Y[k].x = im; }
            }
        }
    }

    // ---- Rot gates (layers 1..3) in (re-based) stored space.
    gates_from<NQ>(X, Y, g00x_r, g00y_r, g01x_r, g01y_r, lane);

    // ---- <Z>: sign(q) = (-1)^parity(sgn' & q)
    const int sl = __popc(PLN.sgn & 63 & lane) & 1;
    const float bsign = sl ? -1.f : 1.f;
    const int sb = (PLN.sgn >> 6) & 15;
    float acc = 0.f;
    #pragma unroll
    for (int k = 0; k < NPK; ++k) {
        const int c0 = __popc(sb & (2 * k)) & 1;               // compile-time
        const int c1 = c0 ^ (sb & 1);
        f32x2 mag = X[k] * X[k] + Y[k] * Y[k];
        acc = fmaf(mag.x, c0 ? -bsign : bsign, acc);
        acc = fmaf(mag.y, c1 ? -bsign : bsign, acc);
    }
    acc += xdpp<1>(acc);
    acc += xdpp<2>(acc);
    acc += xdpp<4>(acc);
    acc += xdpp<8>(acc);
    acc += xswz<16>(acc);
    acc += xbp((lane ^ 32) << 2, acc);
    if (lane == 0) out[b] = acc;
}

extern "C" void kernel_launch(void* const* d_in, const int* in_sizes, int n_in,
                              void* d_out, int out_size, void* d_ws, size_t ws_size,
                              hipStream_t stream) {
    (void)n_in; (void)d_ws; (void)ws_size; (void)out_size;
    const float* x   = (const float*)d_in[0];   // (2048, 10) float32
    const float* wts = (const float*)d_in[1];   // (4, 10, 3) float32
    float* out = (float*)d_out;                 // (2048, 1) float32
    int B = in_sizes[0] / NQ;                   // 2048
    qnn_kernel<<<B, 64, 0, stream>>>(x, wts, out);
}

// Round 16
// 17.337 us; speedup vs baseline: 1.1972x; 1.0128x over previous
//
#include <hip/hip_runtime.h>
#include <math.h>

#define NQ   10
#define NL   4
#define NPK  8    // 8 f32x2 pairs (SoA packing of adjacent j)

typedef float f32x2 __attribute__((ext_vector_type(2)));

// ---------------------------------------------------------------------------
// Compile-time GF(2) tracking of the CNOT rings.
// stored[q] = amp[L q]; gate on logical bit p pairs {q, q^m}, m = col p of
// L^-1; logical bit value = parity(row_p(L) & q). Layer 0 folded into init.
// Layer-3 gates commuting with <Z> (parity(sgn&m)==0) are deleted.
// ---------------------------------------------------------------------------
struct MaskTab { int m[NL * NQ]; int d[NL * NQ]; bool keep[NL * NQ]; int sgn; bool ok; };

constexpr MaskTab make_masks() {
    MaskTab t{};
    int L[NQ] = {}, Li[NQ] = {};
    for (int p = 0; p < NQ; ++p) { L[p] = 1 << p; Li[p] = 1 << p; }
    for (int l = 0; l < NL; ++l) {
        for (int w = 0; w < NQ; ++w) {
            int p = NQ - 1 - w;
            int mm = 0;
            for (int tt = 0; tt < NQ; ++tt) mm |= ((Li[tt] >> p) & 1) << tt;
            t.m[l * NQ + w] = mm;
            t.d[l * NQ + w] = L[p];
        }
        int r = (l % (NQ - 1)) + 1;
        for (int w = 0; w < NQ; ++w) {           // L <- P_l^-1 L
            int pc = NQ - 1 - w;
            int tq = w + r; if (tq >= NQ) tq -= NQ;
            int pt = NQ - 1 - tq;
            L[pt] ^= L[pc];
        }
        for (int w = 0; w < NQ; ++w) {           // Li <- Li P_l
            int pc = NQ - 1 - w;
            int tq = w + r; if (tq >= NQ) tq -= NQ;
            int pt = NQ - 1 - tq;
            for (int p = 0; p < NQ; ++p)
                Li[p] ^= ((Li[p] >> pt) & 1) << pc;
        }
    }
    t.sgn = L[0];
    for (int gi = 0; gi < NL * NQ; ++gi) {
        if (gi < NQ) { t.keep[gi] = false; continue; }            // layer 0 folded
        if (gi < (NL - 1) * NQ) { t.keep[gi] = true; continue; }
        t.keep[gi] = (__builtin_popcount((unsigned)(t.sgn & t.m[gi])) & 1) != 0;
    }
    bool ok = true;
    for (int p = 0; p < NQ; ++p) {
        int row = 0;
        for (int k = 0; k < NQ; ++k)
            if ((L[p] >> k) & 1) row ^= Li[k];
        if (row != (1 << p)) ok = false;
    }
    t.ok = ok;
    return t;
}

static constexpr MaskTab MK = make_masks();
static_assert(MK.ok, "GF(2) inverse check failed");

// ---------------------------------------------------------------------------
// GF(2) 10x10 matrix utilities + basis-change plan (round-15, verified).
// T remaps stored indices (one exact LDS permute after init); masks m'=T m,
// d'/sgn' via T^-T.
// ---------------------------------------------------------------------------
struct Mat { unsigned c[10]; };

constexpr unsigned mv(const Mat& M, unsigned v) {
    unsigned r = 0;
    for (int i = 0; i < 10; ++i) if ((v >> i) & 1u) r ^= M.c[i];
    return r;
}
constexpr bool minvert(const Mat& A, Mat* out) {
    unsigned rowA[10] = {}, rowI[10] = {};
    for (int r = 0; r < 10; ++r) {
        unsigned ra = 0;
        for (int cc = 0; cc < 10; ++cc) ra |= ((A.c[cc] >> r) & 1u) << cc;
        rowA[r] = ra; rowI[r] = 1u << r;
    }
    for (int col = 0; col < 10; ++col) {
        int piv = -1;
        for (int r = col; r < 10; ++r) if ((rowA[r] >> col) & 1u) { piv = r; break; }
        if (piv < 0) return false;
        unsigned ta = rowA[col]; rowA[col] = rowA[piv]; rowA[piv] = ta;
        unsigned ti = rowI[col]; rowI[col] = rowI[piv]; rowI[piv] = ti;
        for (int r = 0; r < 10; ++r)
            if (r != col && ((rowA[r] >> col) & 1u)) { rowA[r] ^= rowA[col]; rowI[r] ^= rowI[col]; }
    }
    for (int cc = 0; cc < 10; ++cc) {
        unsigned cv = 0;
        for (int r = 0; r < 10; ++r) cv |= ((rowI[r] >> cc) & 1u) << r;
        out->c[cc] = cv;
    }
    return true;
}
constexpr int xcost(unsigned m) {
    unsigned ml = m & 63u;
    if (ml == 0) return 0;          // register-only exchange: free
    if ((ml & 48u) == 0) return 1;  // DPP
    if ((ml & 32u) == 0) return 3;  // ds_swizzle
    return 4;                       // ds_bpermute
}

struct Plan { Mat T, Ti; bool useT; int m[NL * NQ], d[NL * NQ], sgn; bool ok; };

constexpr Plan make_plan() {
    Plan P{};
    P.ok = true;
    unsigned dm[NL * NQ] = {}; int dmc[NL * NQ] = {}; int ndm = 0;
    for (int gi = 0; gi < NL * NQ; ++gi) {
        if (!MK.keep[gi]) continue;
        unsigned m = (unsigned)MK.m[gi];
        int f = -1;
        for (int i = 0; i < ndm; ++i) if (dm[i] == m) { f = i; break; }
        if (f < 0) { dm[ndm] = m; dmc[ndm] = xcost(m); ++ndm; }
        else dmc[f] += xcost(m);
    }
    for (int i = 1; i < ndm; ++i) {
        unsigned vm = dm[i]; int vc = dmc[i]; int j = i;
        while (j > 0 && dmc[j - 1] < vc) { dm[j] = dm[j - 1]; dmc[j] = dmc[j - 1]; --j; }
        dm[j] = vm; dmc[j] = vc;
    }
    unsigned sel[10] = {}; int nsel = 0;
    unsigned gb[10] = {};
    for (int i = 0; i < ndm && nsel < 9; ++i) {
        unsigned r = dm[i];
        for (int b = 9; b >= 0; --b) if (((r >> b) & 1u) && gb[b]) r ^= gb[b];
        if (r == 0) continue;
        int lb = 0;
        for (int b = 9; b >= 0; --b) if ((r >> b) & 1u) { lb = b; break; }
        gb[lb] = r;
        sel[nsel++] = dm[i];
    }
    unsigned comp[10] = {}; int ncomp = 0;
    for (int e = 0; e < 10 && nsel + ncomp < 10; ++e) {
        unsigned r = 1u << e;
        for (int b = 9; b >= 0; --b) if (((r >> b) & 1u) && gb[b]) r ^= gb[b];
        if (r == 0) continue;
        int lb = 0;
        for (int b = 9; b >= 0; --b) if ((r >> b) & 1u) { lb = b; break; }
        gb[lb] = r;
        comp[ncomp++] = 1u << e;
    }
    if (nsel + ncomp != 10) { P.ok = false; return P; }
    const unsigned tord[10] = {64, 128, 256, 512, 1, 2, 4, 8, 16, 32};
    Mat S{}, Tt{};
    for (int i = 0; i < 10; ++i) {
        S.c[i]  = (i < nsel) ? sel[i] : comp[i - nsel];
        Tt.c[i] = tord[i];
    }
    Mat Sinv{};
    if (!minvert(S, &Sinv)) { P.ok = false; return P; }
    for (int i = 0; i < 10; ++i) P.T.c[i] = mv(Tt, Sinv.c[i]);
    if (!minvert(P.T, &P.Ti)) { P.ok = false; return P; }
    for (int i = 0; i < 10; ++i) if (mv(P.T, P.Ti.c[i]) != (1u << i)) P.ok = false;
    int cid = 0, cT = 0;
    for (int gi = 0; gi < NL * NQ; ++gi) {
        if (!MK.keep[gi]) continue;
        cid += xcost((unsigned)MK.m[gi]);
        cT  += xcost(mv(P.T, (unsigned)MK.m[gi]));
    }
    P.useT = (cT + 8 < cid);
    for (int gi = 0; gi < NL * NQ; ++gi) {
        if (P.useT) {
            P.m[gi] = (int)mv(P.T, (unsigned)MK.m[gi]);
            unsigned dd = 0;
            for (int i = 0; i < 10; ++i)
                dd |= (unsigned)(__builtin_popcount((unsigned)MK.d[gi] & P.Ti.c[i]) & 1) << i;
            P.d[gi] = (int)dd;
        } else { P.m[gi] = MK.m[gi]; P.d[gi] = MK.d[gi]; }
    }
    if (P.useT) {
        unsigned ss = 0;
        for (int i = 0; i < 10; ++i)
            ss |= (unsigned)(__builtin_popcount((unsigned)MK.sgn & P.Ti.c[i]) & 1) << i;
        P.sgn = (int)ss;
    } else P.sgn = MK.sgn;
    return P;
}
static constexpr Plan PLN = make_plan();
static_assert(PLN.ok, "basis plan failed");

constexpr unsigned kconstj(int j) {            // reg-bit part of Ti*q'
    unsigned r = 0;
    for (int t = 0; t < 4; ++t) if ((j >> t) & 1) r ^= PLN.Ti.c[6 + t];
    return r;
}

// ---------------------------------------------------------------------------
// Gate execution order: within each layer (gates commute — distinct qubits),
// interleave VALU-class (free/DPP masks) with DS-class (swz/bp masks) so the
// two co-resident waves on a SIMD see complementary-pipe work during each
// other's DS-wait windows. Layers are not reordered across (CNOT rings).
// ---------------------------------------------------------------------------
constexpr bool isDSgate(int gi) {
    unsigned ml = (unsigned)PLN.m[gi] & 63u;
    return ml != 0 && (ml & 48u) != 0;
}
struct Order { int idx[NL * NQ]; int n; };
constexpr Order make_order() {
    Order O{};
    int n = 0;
    for (int l = 0; l < NL; ++l) {
        int va[NQ] = {}, da[NQ] = {}; int nv = 0, nd = 0;
        for (int w = 0; w < NQ; ++w) {
            int gi = l * NQ + w;
            if (!MK.keep[gi]) continue;
            if (isDSgate(gi)) da[nd++] = gi; else va[nv++] = gi;
        }
        int iv = 0, id = 0;
        const int tot = nv + nd;
        for (int t = 0; t < tot; ++t) {
            bool pickDS;
            if (id >= nd) pickDS = false;
            else if (iv >= nv) pickDS = true;
            else pickDS = ((t & 1) == 1);          // V, D, V, D, ...
            O.idx[n++] = pickDS ? da[id++] : va[iv++];
        }
    }
    O.n = n;
    for (int i = n; i < NL * NQ; ++i) O.idx[i] = 0;
    return O;
}
static constexpr Order ORD = make_order();

// ---------------------------------------------------------------------------
// Cross-lane xor-exchange, routed by compile-time mask (R7/R11 optimum):
//   bits 0-3 only  -> 1-2 v_mov_dpp   (VALU pipe)
//   bits 0-4       -> 1 ds_swizzle    (DS pipe, xor BitMode)
//   bit 5 set      -> 1 ds_bpermute   (DS pipe, hoisted addr)
// ---------------------------------------------------------------------------
constexpr int dpp_direct(int m) {
    return m == 1 ? 0xB1 : m == 2 ? 0x4E : m == 3 ? 0x1B :
           m == 7 ? 0x141 : m == 8 ? 0x128 : m == 15 ? 0x140 : 0;
}
constexpr int dpp1(int m) {
    return dpp_direct(m)      ? dpp_direct(m) :
           dpp_direct(m ^ 8)  ? 0x128 :
           dpp_direct(m ^ 15) ? 0x140 : 0x141;
}
constexpr int dpp2(int m) {
    return dpp_direct(m)      ? 0 :
           dpp_direct(m ^ 8)  ? dpp_direct(m ^ 8) :
           dpp_direct(m ^ 15) ? dpp_direct(m ^ 15) : dpp_direct(m ^ 7);
}

template <int M>
__device__ __forceinline__ float xdpp(float v) {
    static_assert((M & ~15) == 0 && M != 0, "dpp mask must be 4-bit");
    int u = __builtin_amdgcn_mov_dpp(__float_as_int(v), dpp1(M), 0xF, 0xF, true);
    if constexpr (dpp2(M) != 0)
        u = __builtin_amdgcn_mov_dpp(u, dpp2(M), 0xF, 0xF, true);
    return __int_as_float(u);
}
template <int M>
__device__ __forceinline__ float xswz(float v) {
    static_assert((M & ~31) == 0 && M != 0, "swizzle mask must be 5-bit");
    return __int_as_float(__builtin_amdgcn_ds_swizzle(__float_as_int(v), (M << 10) | 0x1F));
}
__device__ __forceinline__ float xbp(int bpa, float v) {
    return __int_as_float(__builtin_amdgcn_ds_bpermute(bpa, __float_as_int(v)));
}

__device__ __forceinline__ float fxor(float a, unsigned s) {
    return __uint_as_float(__float_as_uint(a) ^ s);
}
__device__ __forceinline__ f32x2 bc2(float v) { f32x2 r; r.x = v; r.y = v; return r; }
__device__ __forceinline__ f32x2 swap2(f32x2 v) { f32x2 r; r.x = v.y; r.y = v.x; return r; }
__device__ __forceinline__ f32x2 cmul(f32x2 a, f32x2 b) {
    f32x2 r;
    r.x = a.x * b.x - a.y * b.y;
    r.y = a.x * b.y + a.y * b.x;
    return r;
}
__device__ __forceinline__ float rdl(float v, int l) {
    return __uint_as_float((unsigned)__builtin_amdgcn_readlane((int)__float_as_uint(v), l));
}

// ---------------------------------------------------------------------------
// Polynomial sincos (no library calls, no branches).
// ---------------------------------------------------------------------------
__device__ __forceinline__ void sincos_tiny(float a, float* s, float* c) {
    float t = a * a;
    *s = a * fmaf(t, fmaf(t, 8.3333333e-3f, -0.16666667f), 1.0f);
    *c = fmaf(t, fmaf(t, fmaf(t, -1.3888889e-3f, 4.1666668e-2f), -0.5f), 1.0f);
}
__device__ __forceinline__ void sincos_q(float a, float* s, float* c) {
    float h = 0.5f * a, u = h * h;
    float sh = h * fmaf(u, fmaf(u, fmaf(u, -1.9841270e-4f, 8.3333333e-3f), -0.16666667f), 1.0f);
    float ch = fmaf(u, fmaf(u, fmaf(u, fmaf(u, 2.4801587e-5f, -1.3888889e-3f),
                                    4.1666668e-2f), -0.5f), 1.0f);
    *s = 2.0f * sh * ch;
    *c = fmaf(-2.0f * sh, sh, 1.0f);
}

// ---------------------------------------------------------------------------
// One gate on SoA state (masks/d from the basis plan PLN).
// ---------------------------------------------------------------------------
template <int GI>
__device__ __forceinline__ void apply_gate(f32x2 (&X)[NPK], f32x2 (&Y)[NPK],
                                           float g00x_r, float g00y_r,
                                           float g01x_r, float g01y_r, int lane) {
    if constexpr (MK.keep[GI]) {
        constexpr int m     = PLN.m[GI];
        constexpr int d     = PLN.d[GI];
        constexpr int mreg  = (m >> 6) & 15;
        constexpr int mlane = m & 63;
        constexpr int dreg  = (d >> 6) & 15;
        constexpr int dlane = d & 63;
        constexpr int  kreg  = mreg >> 1;
        constexpr bool kswap = (mreg & 1) != 0;
        constexpr bool useDPP = (mlane != 0) && ((mlane & 48) == 0);
        constexpr bool useSWZ = (mlane != 0) && !useDPP && ((mlane & 32) == 0);
        constexpr bool useBP  = (mlane != 0) && !useDPP && !useSWZ;

        const float g00x = rdl(g00x_r, GI);
        const float g00y = rdl(g00y_r, GI);
        const float g01x = rdl(g01x_r, GI);
        const float g01y = rdl(g01y_r, GI);

        const int bl = __popc(dlane & lane) & 1;
        const unsigned s0 = (unsigned)bl << 31;
        const float scy0 = fxor(g00y, s0), pcx0 = fxor(g01x, s0);
        const float scy1 = fxor(scy0, 0x80000000u), pcx1 = fxor(pcx0, 0x80000000u);

        f32x2 scyA, scyB, pcxA, pcxB;
        if constexpr (dreg & 1) {
            scyA.x = scy0; scyA.y = scy1;  scyB.x = scy1; scyB.y = scy0;
            pcxA.x = pcx0; pcxA.y = pcx1;  pcxB.x = pcx1; pcxB.y = pcx0;
        } else {
            scyA = bc2(scy0); scyB = bc2(scy1);
            pcxA = bc2(pcx0); pcxB = bc2(pcx1);
        }
        const f32x2 g00xv = bc2(g00x);
        const f32x2 g01yv = bc2(g01y);

        [[maybe_unused]] int bpa = 0;
        if constexpr (useBP) bpa = (lane ^ mlane) << 2;

        f32x2 pX[NPK], pY[NPK];
        #pragma unroll
        for (int k = 0; k < NPK; ++k) {
            f32x2 px = X[k ^ kreg], py = Y[k ^ kreg];
            if constexpr (kswap) { px = swap2(px); py = swap2(py); }
            if constexpr (useDPP) {
                px.x = xdpp<mlane & 15>(px.x); px.y = xdpp<mlane & 15>(px.y);
                py.x = xdpp<mlane & 15>(py.x); py.y = xdpp<mlane & 15>(py.y);
            } else if constexpr (useSWZ) {
                px.x = xswz<mlane & 31>(px.x); px.y = xswz<mlane & 31>(px.y);
                py.x = xswz<mlane & 31>(py.x); py.y = xswz<mlane & 31>(py.y);
            } else if constexpr (useBP) {
                px.x = xbp(bpa, px.x); px.y = xbp(bpa, px.y);
                py.x = xbp(bpa, py.x); py.y = xbp(bpa, py.y);
            }
            pX[k] = px; pY[k] = py;
        }
        #pragma unroll
        for (int k = 0; k < NPK; ++k) {
            const int vs = __popc(dreg & (2 * k)) & 1;     // compile-time
            const f32x2 scyv = vs ? scyB : scyA;
            const f32x2 pcxv = vs ? pcxB : pcxA;
            const f32x2 sX = X[k], sY = Y[k];
            f32x2 nX = sX * g00xv;
            nX -= scyv * sY;
            nX += pcxv * pX[k];
            nX -= g01yv * pY[k];
            f32x2 nY = sY * g00xv;
            nY += scyv * sX;
            nY += pcxv * pY[k];
            nY += g01yv * pX[k];
            X[k] = nX; Y[k] = nY;
        }
    }
}

template <int POS>
__device__ __forceinline__ void gates_from(f32x2 (&X)[NPK], f32x2 (&Y)[NPK],
                                           float g00x_r, float g00y_r,
                                           float g01x_r, float g01y_r, int lane) {
    if constexpr (POS < ORD.n) {
        apply_gate<ORD.idx[POS]>(X, Y, g00x_r, g00y_r, g01x_r, g01y_r, lane);
        gates_from<POS + 1>(X, Y, g00x_r, g00y_r, g01x_r, g01y_r, lane);
    }
}

// ---------------------------------------------------------------------------
// One sample per wave. SoA state in VGPRs. One-time LDS basis permute.
// ---------------------------------------------------------------------------
__global__ __launch_bounds__(64, 2) void qnn_kernel(const float* __restrict__ x,
                                                    const float* __restrict__ wts,
                                                    float* __restrict__ out) {
    const int b    = blockIdx.x;
    const int lane = threadIdx.x;

    const int gidx = (lane < NL * NQ) ? lane : 0;
    float g00x_r, g00y_r, g01x_r, g01y_r;
    {
        float phi = wts[gidx * 3 + 0];
        float th  = wts[gidx * 3 + 1];
        float om  = wts[gidx * 3 + 2];
        float st_, ct_; sincos_tiny(0.5f * th, &st_, &ct_);
        float sp,  cp;  sincos_tiny(0.5f * (phi + om), &sp, &cp);
        float sm,  cm;  sincos_tiny(0.5f * (phi - om), &sm, &cm);
        g00x_r =  cp * ct_;  g00y_r = -sp * ct_;
        g01x_r = -cm * st_;  g01y_r = -sm * st_;
    }

    float myc, mys;
    {
        const int w = (lane < NQ) ? lane : 0;
        sincos_q(1.57079632679f * x[b * NQ + w], &mys, &myc);
    }

    f32x2 u0[NQ], u1[NQ];
    #pragma unroll
    for (int w = 0; w < NQ; ++w) {
        const float a  = rdl(g00x_r, w), bb = rdl(g00y_r, w);
        const float c  = rdl(g01x_r, w), dd = rdl(g01y_r, w);
        const float cw = rdl(myc, w),    sw = rdl(mys, w);
        const int p = NQ - 1 - w;
        u0[p].x =  a * cw + dd * sw;
        u0[p].y = bb * cw -  c * sw;
        u1[p].x = -c * cw - bb * sw;
        u1[p].y = dd * cw -  a * sw;
    }

    f32x2 PLn = (lane & 1) ? u1[0] : u0[0];
    #pragma unroll
    for (int p = 1; p < 6; ++p)
        PLn = cmul(PLn, ((lane >> p) & 1) ? u1[p] : u0[p]);

    f32x2 t67[4], r89[4];
    #pragma unroll
    for (int a = 0; a < 4; ++a) {
        f32x2 r = cmul((a & 1) ? u1[6] : u0[6], (a & 2) ? u1[7] : u0[7]);
        t67[a] = cmul(PLn, r);
        r89[a] = cmul((a & 1) ? u1[8] : u0[8], (a & 2) ? u1[9] : u0[9]);
    }

    f32x2 X[NPK], Y[NPK];
    #pragma unroll
    for (int k = 0; k < NPK; ++k) {
        const int j0 = 2 * k, j1 = 2 * k + 1;
        f32x2 a0 = cmul(t67[j0 & 3], r89[j0 >> 2]);
        f32x2 a1 = cmul(t67[j1 & 3], r89[j1 >> 2]);
        X[k].x = a0.x; X[k].y = a1.x;
        Y[k].x = a0.y; Y[k].y = a1.y;
    }

    // ---- one-time basis-change permutation: stored'[q'] = stored[Ti q']
    if constexpr (PLN.useT) {
        __shared__ float lb[2048];                 // (re,im) interleaved, 8 KB
        #pragma unroll
        for (int k = 0; k < NPK; ++k) {
            #pragma unroll
            for (int e = 0; e < 2; ++e) {
                const int q = ((2 * k + e) << 6) | lane;
                lb[2 * q]     = (e ? X[k].y : X[k].x);
                lb[2 * q + 1] = (e ? Y[k].y : Y[k].x);
            }
        }
        __syncthreads();
        unsigned la = 0;
        #pragma unroll
        for (int i = 0; i < 6; ++i)
            la ^= ((lane >> i) & 1) ? PLN.Ti.c[i] : 0u;
        #pragma unroll
        for (int k = 0; k < NPK; ++k) {
            #pragma unroll
            for (int e = 0; e < 2; ++e) {
                const unsigned qs = la ^ kconstj(2 * k + e);
                const float re = lb[2 * qs], im = lb[2 * qs + 1];
                if (e) { X[k].y = re; Y[k].y = im; }
                else   { X[k].x = re; Y[k].x = im; }
            }
        }
    }

    // ---- Rot gates (layers 1..3), class-interleaved order within layers.
    gates_from<0>(X, Y, g00x_r, g00y_r, g01x_r, g01y_r, lane);

    // ---- <Z>: sign(q) = (-1)^parity(sgn' & q)
    const int sl = __popc(PLN.sgn & 63 & lane) & 1;
    const float bsign = sl ? -1.f : 1.f;
    const int sb = (PLN.sgn >> 6) & 15;
    float acc = 0.f;
    #pragma unroll
    for (int k = 0; k < NPK; ++k) {
        const int c0 = __popc(sb & (2 * k)) & 1;               // compile-time
        const int c1 = c0 ^ (sb & 1);
        f32x2 mag = X[k] * X[k] + Y[k] * Y[k];
        acc = fmaf(mag.x, c0 ? -bsign : bsign, acc);
        acc = fmaf(mag.y, c1 ? -bsign : bsign, acc);
    }
    acc += xdpp<1>(acc);
    acc += xdpp<2>(acc);
    acc += xdpp<4>(acc);
    acc += xdpp<8>(acc);
    acc += xswz<16>(acc);
    acc += xbp((lane ^ 32) << 2, acc);
    if (lane == 0) out[b] = acc;
}

extern "C" void kernel_launch(void* const* d_in, const int* in_sizes, int n_in,
                              void* d_out, int out_size, void* d_ws, size_t ws_size,
                              hipStream_t stream) {
    (void)n_in; (void)d_ws; (void)ws_size; (void)out_size;
    const float* x   = (const float*)d_in[0];   // (2048, 10) float32
    const float* wts = (const float*)d_in[1];   // (4, 10, 3) float32
    float* out = (float*)d_out;                 // (2048, 1) float32
    int B = in_sizes[0] / NQ;                   // 2048
    qnn_kernel<<<B, 64, 0, stream>>>(x, wts, out);
}